// Round 1
// baseline (245.945 us; speedup 1.0000x reference)
//
#include <hip/hip_runtime.h>

typedef __bf16 bf16_t;
typedef __bf16 bf16x8 __attribute__((ext_vector_type(8)));
typedef float f32x4 __attribute__((ext_vector_type(4)));

#define B_   2
#define T_   2048
#define C_   768
#define NH_  12
#define HS_  64
#define N3_  2304
#define M_   4096

__device__ __forceinline__ bf16_t f2bf(float f) {
  unsigned u = __builtin_bit_cast(unsigned, f);
  u += 0x7fffu + ((u >> 16) & 1u);           // round-to-nearest-even
  unsigned short s = (unsigned short)(u >> 16);
  return __builtin_bit_cast(bf16_t, s);
}

// ---------------- fp32 -> bf16 cast of x ----------------
__global__ __launch_bounds__(256) void cvt_x_kernel(const float* __restrict__ x,
                                                    bf16_t* __restrict__ xb) {
  int i = (blockIdx.x * 256 + threadIdx.x) * 4;
  float4 v = *reinterpret_cast<const float4*>(x + i);
  xb[i + 0] = f2bf(v.x);
  xb[i + 1] = f2bf(v.y);
  xb[i + 2] = f2bf(v.z);
  xb[i + 3] = f2bf(v.w);
}

// ---------------- w [K][N] fp32 -> wt [N][K] bf16 (transpose+cast) ----------------
__global__ __launch_bounds__(256) void cvt_w_kernel(const float* __restrict__ w,
                                                    bf16_t* __restrict__ wt) {
  __shared__ float tile[32][33];
  int k0 = blockIdx.x * 32, n0 = blockIdx.y * 32;
  int tx = threadIdx.x, ty = threadIdx.y;  // 32 x 8
#pragma unroll
  for (int i = 0; i < 4; i++)
    tile[ty + i * 8][tx] = w[(size_t)(k0 + ty + i * 8) * N3_ + n0 + tx];
  __syncthreads();
#pragma unroll
  for (int i = 0; i < 4; i++)
    wt[(size_t)(n0 + ty + i * 8) * C_ + k0 + tx] = f2bf(tile[tx][ty + i * 8]);
}

// ---------------- qkv = xb @ wt^T + b, scattered to q/k/v [B,NH,T,HS] bf16 ----------------
__global__ __launch_bounds__(256) void gemm_qkv(const bf16_t* __restrict__ xb,
                                                const bf16_t* __restrict__ wt,
                                                const float* __restrict__ bias,
                                                bf16_t* __restrict__ qout,
                                                bf16_t* __restrict__ kout,
                                                bf16_t* __restrict__ vout) {
  __shared__ bf16_t As[128][40];   // [m][k], pad 32->40 (2-way bank alias only)
  __shared__ bf16_t Bs[128][40];   // [n][k]
  const int tid = threadIdx.x;
  const int lane = tid & 63, wave = tid >> 6;
  const int wm = wave >> 1, wn = wave & 1;
  const int quad = lane >> 4, l15 = lane & 15;
  const int row0 = blockIdx.y * 128;
  const int col0 = blockIdx.x * 128;

  f32x4 acc[4][4];
#pragma unroll
  for (int mi = 0; mi < 4; mi++)
#pragma unroll
    for (int ni = 0; ni < 4; ni++) acc[mi][ni] = f32x4{0.f, 0.f, 0.f, 0.f};

  for (int k0 = 0; k0 < C_; k0 += 32) {
#pragma unroll
    for (int c = 0; c < 2; c++) {
      int chunk = tid + c * 256;          // 0..511
      int r = chunk >> 2, qd = chunk & 3; // 128 rows x 4 chunks of 8 bf16
      *reinterpret_cast<float4*>(&As[r][qd * 8]) =
          *reinterpret_cast<const float4*>(xb + (size_t)(row0 + r) * C_ + k0 + qd * 8);
      *reinterpret_cast<float4*>(&Bs[r][qd * 8]) =
          *reinterpret_cast<const float4*>(wt + (size_t)(col0 + r) * C_ + k0 + qd * 8);
    }
    __syncthreads();

    bf16x8 af[4], bfr[4];
#pragma unroll
    for (int mi = 0; mi < 4; mi++)
      af[mi] = *reinterpret_cast<const bf16x8*>(&As[wm * 64 + mi * 16 + l15][quad * 8]);
#pragma unroll
    for (int ni = 0; ni < 4; ni++)
      bfr[ni] = *reinterpret_cast<const bf16x8*>(&Bs[wn * 64 + ni * 16 + l15][quad * 8]);
#pragma unroll
    for (int mi = 0; mi < 4; mi++)
#pragma unroll
      for (int ni = 0; ni < 4; ni++)
        acc[mi][ni] = __builtin_amdgcn_mfma_f32_16x16x32_bf16(af[mi], bfr[ni], acc[mi][ni], 0, 0, 0);
    __syncthreads();
  }

  // epilogue: bias + cast + scatter into head layout
#pragma unroll
  for (int mi = 0; mi < 4; mi++) {
    int trow = row0 + wm * 64 + mi * 16 + quad * 4;
#pragma unroll
    for (int ni = 0; ni < 4; ni++) {
      int cN = col0 + wn * 64 + ni * 16 + l15;
      int which = cN / 768;
      int rem = cN - which * 768;
      int h = rem >> 6, d = rem & 63;
      bf16_t* dst = (which == 0) ? qout : (which == 1) ? kout : vout;
      float bv = bias[cN];
#pragma unroll
      for (int r = 0; r < 4; r++) {
        int t = trow + r;
        int b = t >> 11, tt = t & 2047;
        dst[(((size_t)b * NH_ + h) * T_ + tt) * HS_ + d] = f2bf(acc[mi][ni][r] + bv);
      }
    }
  }
}

// ---------------- flash attention: block = (b, h, 64-row q tile), 4 waves x 16 q rows ----------------
__global__ __launch_bounds__(256) void attn_kernel(const bf16_t* __restrict__ qb,
                                                   const bf16_t* __restrict__ kb,
                                                   const bf16_t* __restrict__ vb,
                                                   float* __restrict__ out) {
  __shared__ bf16_t Ks[64][72];      // [j][d]
  __shared__ bf16_t Vt[64][72];      // [d][j]  (V transposed)
  __shared__ bf16_t Ps[4][16][72];   // per-wave P in A-layout source [q][j]
  const int tid = threadIdx.x;
  const int lane = tid & 63, wave = tid >> 6;
  const int quad = lane >> 4, l15 = lane & 15;
  const int qtile = blockIdx.x;
  const size_t bh = (size_t)blockIdx.z * NH_ + blockIdx.y;
  const bf16_t* Qg = qb + bh * T_ * HS_;
  const bf16_t* Kgb = kb + bh * T_ * HS_;
  const bf16_t* Vgb = vb + bh * T_ * HS_;

  // Q A-fragments (held for the whole k loop)
  const int qrowA = qtile * 64 + wave * 16 + l15;
  bf16x8 aq0 = *reinterpret_cast<const bf16x8*>(Qg + (size_t)qrowA * HS_ + quad * 8);
  bf16x8 aq1 = *reinterpret_cast<const bf16x8*>(Qg + (size_t)qrowA * HS_ + 32 + quad * 8);

  const int qrow0 = qtile * 64 + wave * 16 + quad * 4;  // + r = global q row (C-layout)
  float m_r[4], l_r[4];
  f32x4 Oacc[4];
#pragma unroll
  for (int r = 0; r < 4; r++) { m_r[r] = -3.0e38f; l_r[r] = 0.f; }
#pragma unroll
  for (int ni = 0; ni < 4; ni++) Oacc[ni] = f32x4{0.f, 0.f, 0.f, 0.f};

  const int nkt = qtile + 1;
  for (int kt = 0; kt < nkt; kt++) {
    const bf16_t* Kg = Kgb + (size_t)kt * 64 * HS_;
    const bf16_t* Vg = Vgb + (size_t)kt * 64 * HS_;
#pragma unroll
    for (int c = 0; c < 2; c++) {
      int chunk = tid + c * 256;           // 64 rows x 8 chunks of 8 bf16
      int r = chunk >> 3, qd = chunk & 7;
      *reinterpret_cast<float4*>(&Ks[r][qd * 8]) =
          *reinterpret_cast<const float4*>(Kg + r * 64 + qd * 8);
      bf16x8 vv = *reinterpret_cast<const bf16x8*>(Vg + r * 64 + qd * 8);
#pragma unroll
      for (int i = 0; i < 8; i++) Vt[qd * 8 + i][r] = vv[i];
    }
    __syncthreads();

    // S = Q K^T  (16 q x 64 j per wave)
    f32x4 sv[4];
#pragma unroll
    for (int ni = 0; ni < 4; ni++) {
      bf16x8 bk0 = *reinterpret_cast<const bf16x8*>(&Ks[ni * 16 + l15][quad * 8]);
      bf16x8 bk1 = *reinterpret_cast<const bf16x8*>(&Ks[ni * 16 + l15][32 + quad * 8]);
      f32x4 s = {0.f, 0.f, 0.f, 0.f};
      s = __builtin_amdgcn_mfma_f32_16x16x32_bf16(aq0, bk0, s, 0, 0, 0);
      s = __builtin_amdgcn_mfma_f32_16x16x32_bf16(aq1, bk1, s, 0, 0, 0);
      sv[ni] = s;
    }

    // scale + causal mask + row max
    float mcur[4];
#pragma unroll
    for (int r = 0; r < 4; r++) mcur[r] = -3.0e38f;
    const bool diag = (kt == qtile);
#pragma unroll
    for (int ni = 0; ni < 4; ni++)
#pragma unroll
      for (int r = 0; r < 4; r++) {
        float s = sv[ni][r] * 0.125f;
        if (diag && (kt * 64 + ni * 16 + l15 > qrow0 + r)) s = -3.0e38f;
        sv[ni][r] = s;
        mcur[r] = fmaxf(mcur[r], s);
      }
#pragma unroll
    for (int off = 1; off < 16; off <<= 1)
#pragma unroll
      for (int r = 0; r < 4; r++)
        mcur[r] = fmaxf(mcur[r], __shfl_xor(mcur[r], off, 64));

    // online softmax update
    float alpha[4], psum[4];
#pragma unroll
    for (int r = 0; r < 4; r++) {
      float mn = fmaxf(m_r[r], mcur[r]);
      alpha[r] = __expf(m_r[r] - mn);
      m_r[r] = mn;
      psum[r] = 0.f;
    }
#pragma unroll
    for (int ni = 0; ni < 4; ni++)
#pragma unroll
      for (int r = 0; r < 4; r++) {
        float p = __expf(sv[ni][r] - m_r[r]);
        sv[ni][r] = p;
        psum[r] += p;
      }
#pragma unroll
    for (int off = 1; off < 16; off <<= 1)
#pragma unroll
      for (int r = 0; r < 4; r++) psum[r] += __shfl_xor(psum[r], off, 64);
#pragma unroll
    for (int r = 0; r < 4; r++) l_r[r] = l_r[r] * alpha[r] + psum[r];
#pragma unroll
    for (int ni = 0; ni < 4; ni++)
#pragma unroll
      for (int r = 0; r < 4; r++) Oacc[ni][r] *= alpha[r];

    // P: C-layout regs -> LDS [q][j] (A-layout source)
#pragma unroll
    for (int ni = 0; ni < 4; ni++)
#pragma unroll
      for (int r = 0; r < 4; r++)
        Ps[wave][quad * 4 + r][ni * 16 + l15] = f2bf(sv[ni][r]);
    __syncthreads();

    // O += P V
#pragma unroll
    for (int kk = 0; kk < 2; kk++) {
      bf16x8 ap = *reinterpret_cast<const bf16x8*>(&Ps[wave][l15][kk * 32 + quad * 8]);
#pragma unroll
      for (int ni = 0; ni < 4; ni++) {
        bf16x8 bv = *reinterpret_cast<const bf16x8*>(&Vt[ni * 16 + l15][kk * 32 + quad * 8]);
        Oacc[ni] = __builtin_amdgcn_mfma_f32_16x16x32_bf16(ap, bv, Oacc[ni], 0, 0, 0);
      }
    }
    __syncthreads();
  }

  // epilogue: normalize and store fp32 [B,NH,T,HS]
#pragma unroll
  for (int ni = 0; ni < 4; ni++)
#pragma unroll
    for (int r = 0; r < 4; r++) {
      float o = Oacc[ni][r] / l_r[r];
      out[(bh * T_ + qrow0 + r) * HS_ + ni * 16 + l15] = o;
    }
}

extern "C" void kernel_launch(void* const* d_in, const int* in_sizes, int n_in,
                              void* d_out, int out_size, void* d_ws, size_t ws_size,
                              hipStream_t stream) {
  const float* x = (const float*)d_in[0];
  const float* w = (const float*)d_in[1];
  const float* bias = (const float*)d_in[2];
  float* out = (float*)d_out;

  char* ws = (char*)d_ws;
  bf16_t* xb = (bf16_t*)(ws);                                   // 4096*768*2   = 6291456
  bf16_t* wt = (bf16_t*)(ws + 6291456);                         // 2304*768*2   = 3538944
  bf16_t* qb = (bf16_t*)(ws + 6291456 + 3538944);               // 3145728*2
  bf16_t* kb = qb + 3145728;
  bf16_t* vb = kb + 3145728;

  cvt_x_kernel<<<dim3((M_ * C_) / 1024), dim3(256), 0, stream>>>(x, xb);
  cvt_w_kernel<<<dim3(C_ / 32, N3_ / 32), dim3(32, 8), 0, stream>>>(w, wt);
  gemm_qkv<<<dim3(N3_ / 128, M_ / 128), dim3(256), 0, stream>>>(xb, wt, bias, qb, kb, vb);
  attn_kernel<<<dim3(T_ / 64, NH_, B_), dim3(256), 0, stream>>>(qb, kb, vb, out);
}